// Round 11
// baseline (186.198 us; speedup 1.0000x reference)
//
#include <hip/hip_runtime.h>

#define Bb 2
#define Nn 256
#define Dd 128
#define Rr 32

typedef unsigned short u16;
typedef unsigned int   u32;
typedef __attribute__((ext_vector_type(8))) short bf16x8;
typedef __attribute__((ext_vector_type(4))) float f32x4;
typedef __attribute__((ext_vector_type(2))) u32   u32x2;
typedef __attribute__((ext_vector_type(4))) u32   u32x4;

// one-time bf16-transposed radial weights (fragment-order), filled by prep_kernel
__device__ u16 g_w1t[4*Dd*Rr];   // per p: W1T[dd*32 + kk] = bf16(W1[kk][dd])
__device__ u16 g_w2t[4*Dd*Dd];   // per p: W2T[dd*128 + kk] = bf16(W2[kk][dd])

__device__ __forceinline__ short f2bfs(float f){
  u32 u = __float_as_uint(f);
  u += 0x7FFFu + ((u >> 16) & 1u);   // RNE
  return (short)(u >> 16);
}
__device__ __forceinline__ u16 f2bf(float f){
  u32 u = __float_as_uint(f);
  u += 0x7FFFu + ((u >> 16) & 1u);
  return (u16)(u >> 16);
}
// packed f32x2 -> bf16x2 (RNE), one VALU op
__device__ __forceinline__ u32 cvtpk(float a, float b){
  u32 r;
  asm("v_cvt_pk_bf16_f32 %0, %1, %2" : "=v"(r) : "v"(a), "v"(b));
  return r;
}

// ---- prep: blocks [0,512): h = node_s @ src_w, stored TRANSPOSED h_T[b][d][i]
//      blocks [512,544): weight bf16-transpose
__global__ __launch_bounds__(128) void prep_kernel(
    const float* __restrict__ node_s, const float* __restrict__ src_w,
    const float* __restrict__ r0w1, const float* __restrict__ r1w1,
    const float* __restrict__ r2w1, const float* __restrict__ r3w1,
    const float* __restrict__ r0w2, const float* __restrict__ r1w2,
    const float* __restrict__ r2w2, const float* __restrict__ r3w2,
    float* __restrict__ h_out)
{
  const int bx = blockIdx.x;
  const int t  = threadIdx.x;
  if (bx < Bb*Nn){
    __shared__ float s_row[Dd];
    s_row[t] = node_s[(size_t)bx*Dd + t];
    __syncthreads();
    float acc = 0.f;
    #pragma unroll 8
    for (int k=0;k<Dd;k++) acc += s_row[k]*src_w[k*Dd + t];
    const int b = bx >> 8, i = bx & 255;
    h_out[(size_t)(b*Dd + t)*Nn + i] = acc;       // transposed: [b][d][i]
  } else {
    const int kb = bx - Bb*Nn;          // 0..31
    const int p  = kb >> 3, sl = kb & 7;
    const float* W1 = (p==0)?r0w1:(p==1)?r1w1:(p==2)?r2w1:r3w1;
    const float* W2 = (p==0)?r0w2:(p==1)?r1w2:(p==2)?r2w2:r3w2;
    u16* W1T = g_w1t + p*Dd*Rr;
    u16* W2T = g_w2t + p*Dd*Dd;
    // coalesced reads (linear in), scattered writes (stores don't stall)
    #pragma unroll
    for (int it=0; it<4; it++){
      int in = sl*512 + it*128 + t;                  // in = kk*Dd + dd
      W1T[(in & 127)*Rr + (in >> 7)] = f2bf(W1[in]);
    }
    #pragma unroll
    for (int it=0; it<16; it++){
      int in = sl*2048 + it*128 + t;                 // in = kk*Dd + dd
      W2T[(in & 127)*Dd + (in >> 7)] = f2bf(W2[in]);
    }
  }
}

// ---- main: 8 waves/block, 512 thr, (512,4). Wave w owns d-cols [w*16,+16),
// all j. Pipelined: each barrier region = {GEMM1(t+1)->buf^1 ; GEMM2(t)<-buf}.
// r10 established: static LDS addressing (ch unrolled, base+immediate), odd
// row stride 130 (bank-spread, no swizzle), zero-row mask -> VALUBusy 52->36,
// conflicts 6.9M->2.2M, BUT hql[2][2] prefetch pushed live set past the
// 128-reg (512,4) budget -> 18MB scratch spill. r11: hql -> single f32x4
// loaded per (g,mm) right after the af loads (MFMA chain + TLP hide L2
// latency; r8 ran this pattern clean at VGPR 52). Peak live ~115 regs.
__global__ __launch_bounds__(512,4) void se3_mfma15(
    const float* __restrict__ node_v,
    const float* __restrict__ rbf,
    const float* __restrict__ r_hat,
    const float* __restrict__ maskp,
    const float* __restrict__ r0b1, const float* __restrict__ r0b2,
    const float* __restrict__ r1b1, const float* __restrict__ r1b2,
    const float* __restrict__ r2b1, const float* __restrict__ r2b2,
    const float* __restrict__ r3b1, const float* __restrict__ r3b2,
    const float* __restrict__ ln_g, const float* __restrict__ ln_b,
    const float* __restrict__ out_w, const float* __restrict__ out_b,
    const float* __restrict__ v_scale, const float* __restrict__ t_scale,
    const float* __restrict__ h_ws,
    float* __restrict__ out_s, float* __restrict__ out_v, float* __restrict__ out_t)
{
  __shared__ u16   s_rbf[Nn*40];       // 20480: rbf bf16, row stride 40
  __shared__ u16   s_hid[2*64*130];    // 33280: dbuf, row stride 130 (odd dwords)
  __shared__ u16   s_YT[11*264];       //  5808: rows 0..9 = Y*mask, row 10 = zeros
  __shared__ u16   s_Y1r[3*264];       //  1584
  __shared__ float s_msg[Dd];          //   512
  __shared__ float s_xn[Dd];           //   512
  __shared__ float s_part[4*Dd];       //  2048
  __shared__ float s_mv[2];            //     8  -> total 64232 B (2 blocks/CU)

  const int tid  = threadIdx.x;
  const int bi   = blockIdx.x;            // b*N + i
  const int b    = bi >> 8;
  const int lane = tid & 63;
  const int w    = tid >> 6;              // wave 0..7
  const int q    = lane >> 4;
  const int cc   = lane & 15;
  const int hi5  = cc >> 2, lo2 = cc & 3;
  const int dwb  = w*16;                  // this wave's 16-col d-base

  // ---- setup: stacked-Y rows (mask folded), raw Y1, zero row ----
  if (tid < Nn){
    int j = tid;
    size_t pidx = (size_t)bi*Nn + j;
    float mk = maskp[pidx];
    float x = r_hat[pidx*3+0];
    float y = r_hat[pidx*3+1];
    float z = r_hat[pidx*3+2];
    const float SQ3=1.7320508075688772f;
    const float C15=3.8729833462074170f;
    const float C5H=1.1180339887498949f;
    float y1a=SQ3*x, y1b=SQ3*y, y1c=SQ3*z;
    s_YT[0*264+j]=f2bf(mk);
    s_YT[1*264+j]=f2bf(y1a*mk);
    s_YT[2*264+j]=f2bf(y1b*mk);
    s_YT[3*264+j]=f2bf(y1c*mk);
    s_YT[4*264+j]=f2bf(C15*x*y*mk);
    s_YT[5*264+j]=f2bf(C15*y*z*mk);
    s_YT[6*264+j]=f2bf(C5H*(3.f*z*z-1.f)*mk);
    s_YT[7*264+j]=f2bf(C15*x*z*mk);
    s_YT[8*264+j]=f2bf(0.5f*C15*(x*x-y*y)*mk);
    s_YT[9*264+j]=f2bf(mk);
    s_YT[10*264+j]=0;                     // zero row for masked-off lanes
    s_Y1r[0*264+j]=f2bf(y1a);
    s_Y1r[1*264+j]=f2bf(y1b);
    s_Y1r[2*264+j]=f2bf(y1c);
  }

  const float* rbf_blk = rbf + (size_t)bi*Nn*Rr;
  const float* htb     = h_ws + (size_t)b*Dd*Nn;   // h_T[b][d][i]

  // ---- stage rbf as bf16 (row stride 40): packed pairs ----
  for (int idx=tid; idx<Nn*Rr/2; idx+=512){
    int j = idx >> 4, r2 = (idx & 15)*2;
    const float* src = &rbf_blk[j*Rr + r2];
    float v0 = src[0], v1 = src[1];
    *(u32*)&s_rbf[j*40 + r2] = cvtpk(v0, v1);
  }

  // ---- node_v B-fragment for the dot MFMA (wave's 16 d-cols) ----
  bf16x8 vBf;
  {
    const float* nv = node_v + (size_t)bi*3*Dd;
    int dd = dwb+cc;
    bf16x8 t = {0,0,0,0,0,0,0,0};
    if (q==0){
      t[0]=f2bfs(nv[0*Dd+dd]);
      t[1]=f2bfs(nv[1*Dd+dd]);
      t[2]=f2bfs(nv[2*Dd+dd]);
    }
    vBf=t;
  }

  // ---- per-lane LDS u16-index bases (all accesses = base + literal) ----
  const int rbf_base = cc*40 + q*8;                 // + ch*2560 + jt*640
  const int hw_base  = cc*130 + w*16 + q*4;         // + buf*8320 + jt*2080
  const int af_base  = (hi5*8+lo2)*130 + q*8;       // + buf*8320 + g*4160 + mm*520 + ks*32

  __syncthreads();                       // setup + staging visible

  const f32x4 zf = {0.f,0.f,0.f,0.f};
  f32x4 accred = zf;

  // pipeline registers
  bf16x8 w1f;  f32x4 b1v4;               // GEMM1 weights of the pending chunk's p
  bf16x8 w2f[4]; float b2v;
  const u16* ytq;                        // per-p Y row base (+q*8 folded)

  auto do_gemm1 = [&](int chn, int bufn){
    #pragma unroll
    for (int jt=0;jt<4;jt++){
      bf16x8 rbff = *(const bf16x8*)&s_rbf[rbf_base + chn*2560 + jt*640];
      f32x4 hc = __builtin_amdgcn_mfma_f32_16x16x32_bf16(w1f, rbff, zf, 0,0,0);
      float s0,s1,s2,s3;
      {
        float x0=hc[0]+b1v4[0], x1=hc[1]+b1v4[1], x2=hc[2]+b1v4[2], x3=hc[3]+b1v4[3];
        s0 = x0*__builtin_amdgcn_rcpf(1.f+__expf(-x0));
        s1 = x1*__builtin_amdgcn_rcpf(1.f+__expf(-x1));
        s2 = x2*__builtin_amdgcn_rcpf(1.f+__expf(-x2));
        s3 = x3*__builtin_amdgcn_rcpf(1.f+__expf(-x3));
      }
      u32x2 pk = { cvtpk(s0, s1), cvtpk(s2, s3) };
      *(u32x2*)&s_hid[bufn*8320 + hw_base + jt*2080] = pk;
    }
  };

  auto do_gemm2 = [&](int chx, int bufx, int p){
    #pragma unroll
    for (int g=0; g<2; g++){
      u32 bB[4];
      #pragma unroll
      for (int mm=0;mm<2;mm++){
        bf16x8 af[4];
        #pragma unroll
        for (int ks=0;ks<4;ks++)
          af[ks] = *(const bf16x8*)&s_hid[bufx*8320 + af_base + g*4160 + mm*520 + ks*32];

        // issue the h load now (4 regs); MFMA chain below covers its latency
        f32x4 hq;
        if (p<3)
          hq = *(const f32x4*)&htb[(size_t)(dwb+cc)*Nn + chx*64 + g*32 + q*8 + mm*4];

        f32x4 dotC;
        if (p==3){                       // dot(v, Y1): A rows follow the tile perm
          bf16x8 aY = {0,0,0,0,0,0,0,0};
          if (q==0){
            int jg = chx*64 + g*32 + hi5*8 + mm*4 + lo2;
            aY[0]=(short)s_Y1r[0*264+jg];
            aY[1]=(short)s_Y1r[1*264+jg];
            aY[2]=(short)s_Y1r[2*264+jg];
          }
          dotC = __builtin_amdgcn_mfma_f32_16x16x32_bf16(aY, vBf, zf, 0,0,0);
        }

        f32x4 c2 = zf;
        #pragma unroll
        for (int ks=0;ks<4;ks++)
          c2 = __builtin_amdgcn_mfma_f32_16x16x32_bf16(af[ks], w2f[ks], c2, 0,0,0);
        float g0,g1,g2,g3;
        if (p<3){
          g0=(c2[0]+b2v)*hq[0]; g1=(c2[1]+b2v)*hq[1];
          g2=(c2[2]+b2v)*hq[2]; g3=(c2[3]+b2v)*hq[3];
        } else {
          g0=(c2[0]+b2v)*dotC[0]; g1=(c2[1]+b2v)*dotC[1];
          g2=(c2[2]+b2v)*dotC[2]; g3=(c2[3]+b2v)*dotC[3];
        }
        bB[mm*2+0] = cvtpk(g0, g1);
        bB[mm*2+1] = cvtpk(g2, g3);
      }
      // j-reduction MFMA over this 32-j group (B-frag from registers)
      bf16x8 aR = *(const bf16x8*)(ytq + chx*64 + g*32);
      u32x4 bw = { bB[0], bB[1], bB[2], bB[3] };
      bf16x8 bG = __builtin_bit_cast(bf16x8, bw);
      accred = __builtin_amdgcn_mfma_f32_16x16x32_bf16(aR, bG, accred, 0,0,0);
    }
  };

  // prologue: p0 GEMM1 weights + chunk 0 -> buf0
  w1f  = *(const bf16x8*)&g_w1t[(dwb+cc)*Rr + q*8];
  b1v4 = *(const f32x4*)&r0b1[dwb + q*4];
  do_gemm1(0, 0);

  #pragma unroll 1
  for (int p=0;p<4;p++){
    // per-p GEMM2-side state (global reads: before barrier, latency overlaps)
    {
      const u16* W2T = g_w2t + p*Dd*Dd;
      #pragma unroll
      for (int ks=0;ks<4;ks++)
        w2f[ks] = *(const bf16x8*)&W2T[(dwb+cc)*Dd + ks*32 + q*8];
      const float* B2p = (p==0)?r0b2:(p==1)?r1b2:(p==2)?r2b2:r3b2;
      b2v = B2p[dwb + cc];
      const int lo = (p==0)?0:(p==1)?1:(p==2)?4:9;
      const int hi = (p==0)?0:(p==1)?3:(p==2)?8:9;
      ytq = &s_YT[((cc>=lo && cc<=hi)?cc:10)*264] + q*8;
    }
    __syncthreads(); do_gemm1(1,1); do_gemm2(0,0,p);
    __syncthreads(); do_gemm1(2,0); do_gemm2(1,1,p);
    __syncthreads(); do_gemm1(3,1); do_gemm2(2,0,p);
    __syncthreads();
    if (p<3){
      w1f  = *(const bf16x8*)&g_w1t[(p+1)*Dd*Rr + (dwb+cc)*Rr + q*8];
      const float* B1n = (p==0)?r1b1:(p==1)?r2b1:r3b1;
      b1v4 = *(const f32x4*)&B1n[dwb + q*4];
      do_gemm1(0,0);
    }
    do_gemm2(3,1,p);
  }

  // ---- scatter accred rows -> outputs / LN inputs (complete per wave) ----
  {
    const int d = dwb + cc;
    #pragma unroll
    for (int r=0;r<4;r++){
      const int rw = q*4 + r;
      float val = accred[r];
      if (rw==0)      s_msg[d] = val;
      else if (rw<=3) out_v[(size_t)bi*3*Dd + (size_t)(rw-1)*Dd + d] = val*v_scale[d];
      else if (rw<=8) out_t[(size_t)bi*5*Dd + (size_t)(rw-4)*Dd + d] = val*t_scale[d];
      else if (rw==9) s_xn[d] = val;
    }
  }
  __syncthreads();

  // ---- LayerNorm stats (wave 0) ----
  if (tid < 64){
    float a0=s_msg[tid]+s_xn[tid], a1=s_msg[tid+64]+s_xn[tid+64];
    float s1=a0+a1, s2=a0*a0+a1*a1;
    #pragma unroll
    for (int off=1;off<64;off<<=1){
      s1 += __shfl_xor(s1,off);
      s2 += __shfl_xor(s2,off);
    }
    if (tid==0){
      float m   = s1*(1.f/Dd);
      float var = fmaxf(s2*(1.f/Dd) - m*m, 0.f);
      s_mv[0]=m;
      s_mv[1]=rsqrtf(var+1e-5f);
    }
  }
  __syncthreads();
  if (tid < Dd){
    float msg = s_msg[tid]+s_xn[tid];
    s_xn[tid] = (msg - s_mv[0])*s_mv[1]*ln_g[tid] + ln_b[tid];
  }
  __syncthreads();

  // ---- delta_s = xn @ out_w + out_b (4 k-segments across 512 threads) ----
  {
    int dp = tid & 127, seg = tid >> 7;
    float pa = 0.f;
    #pragma unroll 8
    for (int k=seg*32;k<seg*32+32;k++)
      pa += s_xn[k]*out_w[k*Dd+dp];
    s_part[seg*Dd+dp]=pa;
  }
  __syncthreads();
  if (tid < Dd)
    out_s[(size_t)bi*Dd+tid] = s_part[tid]+s_part[Dd+tid]+s_part[2*Dd+tid]+s_part[3*Dd+tid]+out_b[tid];
}

extern "C" void kernel_launch(void* const* d_in, const int* in_sizes, int n_in,
                              void* d_out, int out_size, void* d_ws, size_t ws_size,
                              hipStream_t stream) {
  const float* node_s = (const float*)d_in[0];
  const float* node_v = (const float*)d_in[1];
  // d_in[2] = node_t (unused by reference)
  const float* rbf    = (const float*)d_in[3];
  const float* r_hat  = (const float*)d_in[4];
  const float* maskp  = (const float*)d_in[5];
  const float* r0w1=(const float*)d_in[6],  *r0b1=(const float*)d_in[7];
  const float* r0w2=(const float*)d_in[8],  *r0b2=(const float*)d_in[9];
  const float* r1w1=(const float*)d_in[10], *r1b1=(const float*)d_in[11];
  const float* r1w2=(const float*)d_in[12], *r1b2=(const float*)d_in[13];
  const float* r2w1=(const float*)d_in[14], *r2b1=(const float*)d_in[15];
  const float* r2w2=(const float*)d_in[16], *r2b2=(const float*)d_in[17];
  const float* r3w1=(const float*)d_in[18], *r3b1=(const float*)d_in[19];
  const float* r3w2=(const float*)d_in[20], *r3b2=(const float*)d_in[21];
  const float* src_w  =(const float*)d_in[22];
  const float* ln_g   =(const float*)d_in[23];
  const float* ln_b   =(const float*)d_in[24];
  const float* out_w  =(const float*)d_in[25];
  const float* out_b  =(const float*)d_in[26];
  const float* v_scale=(const float*)d_in[27];
  const float* t_scale=(const float*)d_in[28];

  float* h_ws = (float*)d_ws;                    // h_T: 2*128*256 f32 = 256 KiB
  float* out_s = (float*)d_out;
  float* out_v = out_s + (size_t)Bb*Nn*Dd;
  float* out_t = out_v + (size_t)Bb*Nn*3*Dd;

  prep_kernel<<<dim3(Bb*Nn + 32), dim3(128), 0, stream>>>(
      node_s, src_w,
      r0w1, r1w1, r2w1, r3w1, r0w2, r1w2, r2w2, r3w2,
      h_ws);
  se3_mfma15<<<dim3(Bb*Nn), dim3(512), 0, stream>>>(
      node_v, rbf, r_hat, maskp,
      r0b1,r0b2, r1b1,r1b2, r2b1,r2b2, r3b1,r3b2,
      ln_g, ln_b, out_w, out_b, v_scale, t_scale,
      h_ws, out_s, out_v, out_t);
}

// Round 12
// 183.941 us; speedup vs baseline: 1.0123x; 1.0123x over previous
//
#include <hip/hip_runtime.h>

#define Bb 2
#define Nn 256
#define Dd 128
#define Rr 32

typedef unsigned short u16;
typedef unsigned int   u32;
typedef __attribute__((ext_vector_type(8))) short bf16x8;
typedef __attribute__((ext_vector_type(4))) float f32x4;
typedef __attribute__((ext_vector_type(2))) u32   u32x2;
typedef __attribute__((ext_vector_type(4))) u32   u32x4;

// one-time bf16-transposed radial weights (fragment-order), filled by prep_kernel
__device__ u16 g_w1t[4*Dd*Rr];   // per p: W1T[dd*32 + kk] = bf16(W1[kk][dd])
__device__ u16 g_w2t[4*Dd*Dd];   // per p: W2T[dd*128 + kk] = bf16(W2[kk][dd])

__device__ __forceinline__ short f2bfs(float f){
  u32 u = __float_as_uint(f);
  u += 0x7FFFu + ((u >> 16) & 1u);   // RNE
  return (short)(u >> 16);
}
__device__ __forceinline__ u16 f2bf(float f){
  u32 u = __float_as_uint(f);
  u += 0x7FFFu + ((u >> 16) & 1u);
  return (u16)(u >> 16);
}
// packed f32x2 -> bf16x2 (RNE), one VALU op
__device__ __forceinline__ u32 cvtpk(float a, float b){
  u32 r;
  asm("v_cvt_pk_bf16_f32 %0, %1, %2" : "=v"(r) : "v"(a), "v"(b));
  return r;
}

// ---- prep: blocks [0,512): h = node_s @ src_w, stored TRANSPOSED h_T[b][d][i]
//      blocks [512,544): weight bf16-transpose
__global__ __launch_bounds__(128) void prep_kernel(
    const float* __restrict__ node_s, const float* __restrict__ src_w,
    const float* __restrict__ r0w1, const float* __restrict__ r1w1,
    const float* __restrict__ r2w1, const float* __restrict__ r3w1,
    const float* __restrict__ r0w2, const float* __restrict__ r1w2,
    const float* __restrict__ r2w2, const float* __restrict__ r3w2,
    float* __restrict__ h_out)
{
  const int bx = blockIdx.x;
  const int t  = threadIdx.x;
  if (bx < Bb*Nn){
    __shared__ float s_row[Dd];
    s_row[t] = node_s[(size_t)bx*Dd + t];
    __syncthreads();
    float acc = 0.f;
    #pragma unroll 8
    for (int k=0;k<Dd;k++) acc += s_row[k]*src_w[k*Dd + t];
    const int b = bx >> 8, i = bx & 255;
    h_out[(size_t)(b*Dd + t)*Nn + i] = acc;       // transposed: [b][d][i]
  } else {
    const int kb = bx - Bb*Nn;          // 0..31
    const int p  = kb >> 3, sl = kb & 7;
    const float* W1 = (p==0)?r0w1:(p==1)?r1w1:(p==2)?r2w1:r3w1;
    const float* W2 = (p==0)?r0w2:(p==1)?r1w2:(p==2)?r2w2:r3w2;
    u16* W1T = g_w1t + p*Dd*Rr;
    u16* W2T = g_w2t + p*Dd*Dd;
    // coalesced reads (linear in), scattered writes (stores don't stall)
    #pragma unroll
    for (int it=0; it<4; it++){
      int in = sl*512 + it*128 + t;                  // in = kk*Dd + dd
      W1T[(in & 127)*Rr + (in >> 7)] = f2bf(W1[in]);
    }
    #pragma unroll
    for (int it=0; it<16; it++){
      int in = sl*2048 + it*128 + t;                 // in = kk*Dd + dd
      W2T[(in & 127)*Dd + (in >> 7)] = f2bf(W2[in]);
    }
  }
}

// ---- main: 8 waves/block, 512 thr, (512,4). Wave w owns d-cols [w*16,+16),
// all j. Pipelined: each barrier region = {GEMM1(t+1)->buf^1 ; GEMM2(t)<-buf}.
// Static LDS addressing (ch unrolled, base+immediate), odd row stride 130
// (bank-spread, no swizzle), zero-row mask. r12 FIX: the r10/r11 scratch
// spill (WRITE 16-18MB) came from the scheduler hoisting the independent
// global h-loads of ALL FOUR unrolled chunks to the top of the p-body
// (64 VGPRs in flight; r9's rolled loop had no spill with identical loads).
// A zero-cost `asm volatile("" ::: "memory")` at the top of each GEMM2 body
// pins each chunk's h-loads inside its own chunk -> peak in-flight h = 16 regs.
__global__ __launch_bounds__(512,4) void se3_mfma16(
    const float* __restrict__ node_v,
    const float* __restrict__ rbf,
    const float* __restrict__ r_hat,
    const float* __restrict__ maskp,
    const float* __restrict__ r0b1, const float* __restrict__ r0b2,
    const float* __restrict__ r1b1, const float* __restrict__ r1b2,
    const float* __restrict__ r2b1, const float* __restrict__ r2b2,
    const float* __restrict__ r3b1, const float* __restrict__ r3b2,
    const float* __restrict__ ln_g, const float* __restrict__ ln_b,
    const float* __restrict__ out_w, const float* __restrict__ out_b,
    const float* __restrict__ v_scale, const float* __restrict__ t_scale,
    const float* __restrict__ h_ws,
    float* __restrict__ out_s, float* __restrict__ out_v, float* __restrict__ out_t)
{
  __shared__ u16   s_rbf[Nn*40];       // 20480: rbf bf16, row stride 40
  __shared__ u16   s_hid[2*64*130];    // 33280: dbuf, row stride 130 (odd dwords)
  __shared__ u16   s_YT[11*264];       //  5808: rows 0..9 = Y*mask, row 10 = zeros
  __shared__ u16   s_Y1r[3*264];       //  1584
  __shared__ float s_msg[Dd];          //   512
  __shared__ float s_xn[Dd];           //   512
  __shared__ float s_part[4*Dd];       //  2048
  __shared__ float s_mv[2];            //     8  -> total 64232 B (2 blocks/CU)

  const int tid  = threadIdx.x;
  const int bi   = blockIdx.x;            // b*N + i
  const int b    = bi >> 8;
  const int lane = tid & 63;
  const int w    = tid >> 6;              // wave 0..7
  const int q    = lane >> 4;
  const int cc   = lane & 15;
  const int hi5  = cc >> 2, lo2 = cc & 3;
  const int dwb  = w*16;                  // this wave's 16-col d-base

  // ---- setup: stacked-Y rows (mask folded), raw Y1, zero row ----
  if (tid < Nn){
    int j = tid;
    size_t pidx = (size_t)bi*Nn + j;
    float mk = maskp[pidx];
    float x = r_hat[pidx*3+0];
    float y = r_hat[pidx*3+1];
    float z = r_hat[pidx*3+2];
    const float SQ3=1.7320508075688772f;
    const float C15=3.8729833462074170f;
    const float C5H=1.1180339887498949f;
    float y1a=SQ3*x, y1b=SQ3*y, y1c=SQ3*z;
    s_YT[0*264+j]=f2bf(mk);
    s_YT[1*264+j]=f2bf(y1a*mk);
    s_YT[2*264+j]=f2bf(y1b*mk);
    s_YT[3*264+j]=f2bf(y1c*mk);
    s_YT[4*264+j]=f2bf(C15*x*y*mk);
    s_YT[5*264+j]=f2bf(C15*y*z*mk);
    s_YT[6*264+j]=f2bf(C5H*(3.f*z*z-1.f)*mk);
    s_YT[7*264+j]=f2bf(C15*x*z*mk);
    s_YT[8*264+j]=f2bf(0.5f*C15*(x*x-y*y)*mk);
    s_YT[9*264+j]=f2bf(mk);
    s_YT[10*264+j]=0;                     // zero row for masked-off lanes
    s_Y1r[0*264+j]=f2bf(y1a);
    s_Y1r[1*264+j]=f2bf(y1b);
    s_Y1r[2*264+j]=f2bf(y1c);
  }

  const float* rbf_blk = rbf + (size_t)bi*Nn*Rr;
  const float* htb     = h_ws + (size_t)b*Dd*Nn;   // h_T[b][d][i]

  // ---- stage rbf as bf16 (row stride 40): packed pairs ----
  for (int idx=tid; idx<Nn*Rr/2; idx+=512){
    int j = idx >> 4, r2 = (idx & 15)*2;
    const float* src = &rbf_blk[j*Rr + r2];
    float v0 = src[0], v1 = src[1];
    *(u32*)&s_rbf[j*40 + r2] = cvtpk(v0, v1);
  }

  // ---- node_v B-fragment for the dot MFMA (wave's 16 d-cols) ----
  bf16x8 vBf;
  {
    const float* nv = node_v + (size_t)bi*3*Dd;
    int dd = dwb+cc;
    bf16x8 t = {0,0,0,0,0,0,0,0};
    if (q==0){
      t[0]=f2bfs(nv[0*Dd+dd]);
      t[1]=f2bfs(nv[1*Dd+dd]);
      t[2]=f2bfs(nv[2*Dd+dd]);
    }
    vBf=t;
  }

  // ---- per-lane LDS u16-index bases (all accesses = base + literal) ----
  const int rbf_base = cc*40 + q*8;                 // + ch*2560 + jt*640
  const int hw_base  = cc*130 + w*16 + q*4;         // + buf*8320 + jt*2080
  const int af_base  = (hi5*8+lo2)*130 + q*8;       // + buf*8320 + g*4160 + mm*520 + ks*32

  __syncthreads();                       // setup + staging visible

  const f32x4 zf = {0.f,0.f,0.f,0.f};
  f32x4 accred = zf;

  // pipeline registers
  bf16x8 w1f;  f32x4 b1v4;               // GEMM1 weights of the pending chunk's p
  bf16x8 w2f[4]; float b2v;
  const u16* ytq;                        // per-p Y row base (+q*8 folded)

  auto do_gemm1 = [&](int chn, int bufn){
    #pragma unroll
    for (int jt=0;jt<4;jt++){
      bf16x8 rbff = *(const bf16x8*)&s_rbf[rbf_base + chn*2560 + jt*640];
      f32x4 hc = __builtin_amdgcn_mfma_f32_16x16x32_bf16(w1f, rbff, zf, 0,0,0);
      float s0,s1,s2,s3;
      {
        float x0=hc[0]+b1v4[0], x1=hc[1]+b1v4[1], x2=hc[2]+b1v4[2], x3=hc[3]+b1v4[3];
        s0 = x0*__builtin_amdgcn_rcpf(1.f+__expf(-x0));
        s1 = x1*__builtin_amdgcn_rcpf(1.f+__expf(-x1));
        s2 = x2*__builtin_amdgcn_rcpf(1.f+__expf(-x2));
        s3 = x3*__builtin_amdgcn_rcpf(1.f+__expf(-x3));
      }
      u32x2 pk = { cvtpk(s0, s1), cvtpk(s2, s3) };
      *(u32x2*)&s_hid[bufn*8320 + hw_base + jt*2080] = pk;
    }
  };

  auto do_gemm2 = [&](int chx, int bufx, int p){
    // fence: pin this chunk's global h-loads INSIDE this chunk (zero-cost;
    // blocks the scheduler from hoisting them across the unrolled p-body,
    // which was the 16-18MB scratch spill in r10/r11)
    asm volatile("" ::: "memory");
    f32x4 hql[2][2];
    if (p<3){
      #pragma unroll
      for (int g=0;g<2;g++)
        #pragma unroll
        for (int mm=0;mm<2;mm++)
          hql[g][mm] = *(const f32x4*)&htb[(size_t)(dwb+cc)*Nn + chx*64 + g*32 + q*8 + mm*4];
    }
    #pragma unroll
    for (int g=0; g<2; g++){
      u32 bB[4];
      #pragma unroll
      for (int mm=0;mm<2;mm++){
        bf16x8 af[4];
        #pragma unroll
        for (int ks=0;ks<4;ks++)
          af[ks] = *(const bf16x8*)&s_hid[bufx*8320 + af_base + g*4160 + mm*520 + ks*32];

        f32x4 dotC;
        if (p==3){                       // dot(v, Y1): A rows follow the tile perm
          bf16x8 aY = {0,0,0,0,0,0,0,0};
          if (q==0){
            int jg = chx*64 + g*32 + hi5*8 + mm*4 + lo2;
            aY[0]=(short)s_Y1r[0*264+jg];
            aY[1]=(short)s_Y1r[1*264+jg];
            aY[2]=(short)s_Y1r[2*264+jg];
          }
          dotC = __builtin_amdgcn_mfma_f32_16x16x32_bf16(aY, vBf, zf, 0,0,0);
        }

        f32x4 c2 = zf;
        #pragma unroll
        for (int ks=0;ks<4;ks++)
          c2 = __builtin_amdgcn_mfma_f32_16x16x32_bf16(af[ks], w2f[ks], c2, 0,0,0);
        float g0,g1,g2,g3;
        if (p<3){
          g0=(c2[0]+b2v)*hql[g][mm][0]; g1=(c2[1]+b2v)*hql[g][mm][1];
          g2=(c2[2]+b2v)*hql[g][mm][2]; g3=(c2[3]+b2v)*hql[g][mm][3];
        } else {
          g0=(c2[0]+b2v)*dotC[0]; g1=(c2[1]+b2v)*dotC[1];
          g2=(c2[2]+b2v)*dotC[2]; g3=(c2[3]+b2v)*dotC[3];
        }
        bB[mm*2+0] = cvtpk(g0, g1);
        bB[mm*2+1] = cvtpk(g2, g3);
      }
      // j-reduction MFMA over this 32-j group (B-frag from registers)
      bf16x8 aR = *(const bf16x8*)(ytq + chx*64 + g*32);
      u32x4 bw = { bB[0], bB[1], bB[2], bB[3] };
      bf16x8 bG = __builtin_bit_cast(bf16x8, bw);
      accred = __builtin_amdgcn_mfma_f32_16x16x32_bf16(aR, bG, accred, 0,0,0);
    }
  };

  // prologue: p0 GEMM1 weights + chunk 0 -> buf0
  w1f  = *(const bf16x8*)&g_w1t[(dwb+cc)*Rr + q*8];
  b1v4 = *(const f32x4*)&r0b1[dwb + q*4];
  do_gemm1(0, 0);

  #pragma unroll 1
  for (int p=0;p<4;p++){
    // per-p GEMM2-side state (global reads: before barrier, latency overlaps)
    {
      const u16* W2T = g_w2t + p*Dd*Dd;
      #pragma unroll
      for (int ks=0;ks<4;ks++)
        w2f[ks] = *(const bf16x8*)&W2T[(dwb+cc)*Dd + ks*32 + q*8];
      const float* B2p = (p==0)?r0b2:(p==1)?r1b2:(p==2)?r2b2:r3b2;
      b2v = B2p[dwb + cc];
      const int lo = (p==0)?0:(p==1)?1:(p==2)?4:9;
      const int hi = (p==0)?0:(p==1)?3:(p==2)?8:9;
      ytq = &s_YT[((cc>=lo && cc<=hi)?cc:10)*264] + q*8;
    }
    __syncthreads(); do_gemm1(1,1); do_gemm2(0,0,p);
    __syncthreads(); do_gemm1(2,0); do_gemm2(1,1,p);
    __syncthreads(); do_gemm1(3,1); do_gemm2(2,0,p);
    __syncthreads();
    if (p<3){
      w1f  = *(const bf16x8*)&g_w1t[(p+1)*Dd*Rr + (dwb+cc)*Rr + q*8];
      const float* B1n = (p==0)?r1b1:(p==1)?r2b1:r3b1;
      b1v4 = *(const f32x4*)&B1n[dwb + q*4];
      do_gemm1(0,0);
    }
    do_gemm2(3,1,p);
  }

  // ---- scatter accred rows -> outputs / LN inputs (complete per wave) ----
  {
    const int d = dwb + cc;
    #pragma unroll
    for (int r=0;r<4;r++){
      const int rw = q*4 + r;
      float val = accred[r];
      if (rw==0)      s_msg[d] = val;
      else if (rw<=3) out_v[(size_t)bi*3*Dd + (size_t)(rw-1)*Dd + d] = val*v_scale[d];
      else if (rw<=8) out_t[(size_t)bi*5*Dd + (size_t)(rw-4)*Dd + d] = val*t_scale[d];
      else if (rw==9) s_xn[d] = val;
    }
  }
  __syncthreads();

  // ---- LayerNorm stats (wave 0) ----
  if (tid < 64){
    float a0=s_msg[tid]+s_xn[tid], a1=s_msg[tid+64]+s_xn[tid+64];
    float s1=a0+a1, s2=a0*a0+a1*a1;
    #pragma unroll
    for (int off=1;off<64;off<<=1){
      s1 += __shfl_xor(s1,off);
      s2 += __shfl_xor(s2,off);
    }
    if (tid==0){
      float m   = s1*(1.f/Dd);
      float var = fmaxf(s2*(1.f/Dd) - m*m, 0.f);
      s_mv[0]=m;
      s_mv[1]=rsqrtf(var+1e-5f);
    }
  }
  __syncthreads();
  if (tid < Dd){
    float msg = s_msg[tid]+s_xn[tid];
    s_xn[tid] = (msg - s_mv[0])*s_mv[1]*ln_g[tid] + ln_b[tid];
  }
  __syncthreads();

  // ---- delta_s = xn @ out_w + out_b (4 k-segments across 512 threads) ----
  {
    int dp = tid & 127, seg = tid >> 7;
    float pa = 0.f;
    #pragma unroll 8
    for (int k=seg*32;k<seg*32+32;k++)
      pa += s_xn[k]*out_w[k*Dd+dp];
    s_part[seg*Dd+dp]=pa;
  }
  __syncthreads();
  if (tid < Dd)
    out_s[(size_t)bi*Dd+tid] = s_part[tid]+s_part[Dd+tid]+s_part[2*Dd+tid]+s_part[3*Dd+tid]+out_b[tid];
}

extern "C" void kernel_launch(void* const* d_in, const int* in_sizes, int n_in,
                              void* d_out, int out_size, void* d_ws, size_t ws_size,
                              hipStream_t stream) {
  const float* node_s = (const float*)d_in[0];
  const float* node_v = (const float*)d_in[1];
  // d_in[2] = node_t (unused by reference)
  const float* rbf    = (const float*)d_in[3];
  const float* r_hat  = (const float*)d_in[4];
  const float* maskp  = (const float*)d_in[5];
  const float* r0w1=(const float*)d_in[6],  *r0b1=(const float*)d_in[7];
  const float* r0w2=(const float*)d_in[8],  *r0b2=(const float*)d_in[9];
  const float* r1w1=(const float*)d_in[10], *r1b1=(const float*)d_in[11];
  const float* r1w2=(const float*)d_in[12], *r1b2=(const float*)d_in[13];
  const float* r2w1=(const float*)d_in[14], *r2b1=(const float*)d_in[15];
  const float* r2w2=(const float*)d_in[16], *r2b2=(const float*)d_in[17];
  const float* r3w1=(const float*)d_in[18], *r3b1=(const float*)d_in[19];
  const float* r3w2=(const float*)d_in[20], *r3b2=(const float*)d_in[21];
  const float* src_w  =(const float*)d_in[22];
  const float* ln_g   =(const float*)d_in[23];
  const float* ln_b   =(const float*)d_in[24];
  const float* out_w  =(const float*)d_in[25];
  const float* out_b  =(const float*)d_in[26];
  const float* v_scale=(const float*)d_in[27];
  const float* t_scale=(const float*)d_in[28];

  float* h_ws = (float*)d_ws;                    // h_T: 2*128*256 f32 = 256 KiB
  float* out_s = (float*)d_out;
  float* out_v = out_s + (size_t)Bb*Nn*Dd;
  float* out_t = out_v + (size_t)Bb*Nn*3*Dd;

  prep_kernel<<<dim3(Bb*Nn + 32), dim3(128), 0, stream>>>(
      node_s, src_w,
      r0w1, r1w1, r2w1, r3w1, r0w2, r1w2, r2w2, r3w2,
      h_ws);
  se3_mfma16<<<dim3(Bb*Nn), dim3(512), 0, stream>>>(
      node_v, rbf, r_hat, maskp,
      r0b1,r0b2, r1b1,r1b2, r2b1,r2b2, r3b1,r3b2,
      ln_g, ln_b, out_w, out_b, v_scale, t_scale,
      h_ws, out_s, out_v, out_t);
}

// Round 13
// 178.662 us; speedup vs baseline: 1.0422x; 1.0296x over previous
//
#include <hip/hip_runtime.h>

#define Bb 2
#define Nn 256
#define Dd 128
#define Rr 32

typedef unsigned short u16;
typedef unsigned int   u32;
typedef __attribute__((ext_vector_type(8))) short bf16x8;
typedef __attribute__((ext_vector_type(4))) float f32x4;
typedef __attribute__((ext_vector_type(2))) u32   u32x2;
typedef __attribute__((ext_vector_type(4))) u32   u32x4;

// one-time bf16-transposed radial weights (fragment-order), filled by prep_kernel
__device__ u16 g_w1t[4*Dd*Rr];   // per p: W1T[dd*32 + kk] = bf16(W1[kk][dd])
__device__ u16 g_w2t[4*Dd*Dd];   // per p: W2T[dd*128 + kk] = bf16(W2[kk][dd])

__device__ __forceinline__ short f2bfs(float f){
  u32 u = __float_as_uint(f);
  u += 0x7FFFu + ((u >> 16) & 1u);   // RNE
  return (short)(u >> 16);
}
__device__ __forceinline__ u16 f2bf(float f){
  u32 u = __float_as_uint(f);
  u += 0x7FFFu + ((u >> 16) & 1u);
  return (u16)(u >> 16);
}
// packed f32x2 -> bf16x2 (RNE), one VALU op
__device__ __forceinline__ u32 cvtpk(float a, float b){
  u32 r;
  asm("v_cvt_pk_bf16_f32 %0, %1, %2" : "=v"(r) : "v"(a), "v"(b));
  return r;
}

// ---- prep: blocks [0,512): h = node_s @ src_w, stored TRANSPOSED h_T[b][d][i]
//      blocks [512,544): weight bf16-transpose
__global__ __launch_bounds__(128) void prep_kernel(
    const float* __restrict__ node_s, const float* __restrict__ src_w,
    const float* __restrict__ r0w1, const float* __restrict__ r1w1,
    const float* __restrict__ r2w1, const float* __restrict__ r3w1,
    const float* __restrict__ r0w2, const float* __restrict__ r1w2,
    const float* __restrict__ r2w2, const float* __restrict__ r3w2,
    float* __restrict__ h_out)
{
  const int bx = blockIdx.x;
  const int t  = threadIdx.x;
  if (bx < Bb*Nn){
    __shared__ float s_row[Dd];
    s_row[t] = node_s[(size_t)bx*Dd + t];
    __syncthreads();
    float acc = 0.f;
    #pragma unroll 8
    for (int k=0;k<Dd;k++) acc += s_row[k]*src_w[k*Dd + t];
    const int b = bx >> 8, i = bx & 255;
    h_out[(size_t)(b*Dd + t)*Nn + i] = acc;       // transposed: [b][d][i]
  } else {
    const int kb = bx - Bb*Nn;          // 0..31
    const int p  = kb >> 3, sl = kb & 7;
    const float* W1 = (p==0)?r0w1:(p==1)?r1w1:(p==2)?r2w1:r3w1;
    const float* W2 = (p==0)?r0w2:(p==1)?r1w2:(p==2)?r2w2:r3w2;
    u16* W1T = g_w1t + p*Dd*Rr;
    u16* W2T = g_w2t + p*Dd*Dd;
    // coalesced reads (linear in), scattered writes (stores don't stall)
    #pragma unroll
    for (int it=0; it<4; it++){
      int in = sl*512 + it*128 + t;                  // in = kk*Dd + dd
      W1T[(in & 127)*Rr + (in >> 7)] = f2bf(W1[in]);
    }
    #pragma unroll
    for (int it=0; it<16; it++){
      int in = sl*2048 + it*128 + t;                 // in = kk*Dd + dd
      W2T[(in & 127)*Dd + (in >> 7)] = f2bf(W2[in]);
    }
  }
}

// ---- main: 8 waves/block, 512 thr, (512,4). Wave w owns d-cols [w*16,+16),
// all j. Pipelined: each barrier region = {GEMM1(t+1)->buf^1 ; GEMM2(t)<-buf}.
// Static LDS addressing inside the body (base+immediate), odd row stride 130
// (bank-spread, no swizzle), zero-row mask. r13: PAIR-LOOP — the p-body is a
// runtime u in {0,1} loop (unroll 1), each iteration = 2 chunks with static
// buffer roles (buf1 = GEMM1 target of ch 2u+1, buf0 = ch 2u / next even).
// Rationale: the fully-unrolled p-body (r10-r12) spilled ~16MB scratch at the
// (512,4) 128-reg budget no matter what was moved inside it, while the rolled
// r9 loop allocated 52 VGPRs spill-free. Halving the scheduling scope keeps
// r10's static-addressing VALU win AND r9's clean allocation.
__global__ __launch_bounds__(512,4) void se3_mfma17(
    const float* __restrict__ node_v,
    const float* __restrict__ rbf,
    const float* __restrict__ r_hat,
    const float* __restrict__ maskp,
    const float* __restrict__ r0b1, const float* __restrict__ r0b2,
    const float* __restrict__ r1b1, const float* __restrict__ r1b2,
    const float* __restrict__ r2b1, const float* __restrict__ r2b2,
    const float* __restrict__ r3b1, const float* __restrict__ r3b2,
    const float* __restrict__ ln_g, const float* __restrict__ ln_b,
    const float* __restrict__ out_w, const float* __restrict__ out_b,
    const float* __restrict__ v_scale, const float* __restrict__ t_scale,
    const float* __restrict__ h_ws,
    float* __restrict__ out_s, float* __restrict__ out_v, float* __restrict__ out_t)
{
  __shared__ u16   s_rbf[Nn*40];       // 20480: rbf bf16, row stride 40
  __shared__ u16   s_hid[2*64*130];    // 33280: dbuf, row stride 130 (odd dwords)
  __shared__ u16   s_YT[11*264];       //  5808: rows 0..9 = Y*mask, row 10 = zeros
  __shared__ u16   s_Y1r[3*264];       //  1584
  __shared__ float s_msg[Dd];          //   512
  __shared__ float s_xn[Dd];           //   512
  __shared__ float s_part[4*Dd];       //  2048
  __shared__ float s_mv[2];            //     8  -> total 64232 B (2 blocks/CU)

  const int tid  = threadIdx.x;
  const int bi   = blockIdx.x;            // b*N + i
  const int b    = bi >> 8;
  const int lane = tid & 63;
  const int w    = tid >> 6;              // wave 0..7
  const int q    = lane >> 4;
  const int cc   = lane & 15;
  const int hi5  = cc >> 2, lo2 = cc & 3;
  const int dwb  = w*16;                  // this wave's 16-col d-base

  // ---- setup: stacked-Y rows (mask folded), raw Y1, zero row ----
  if (tid < Nn){
    int j = tid;
    size_t pidx = (size_t)bi*Nn + j;
    float mk = maskp[pidx];
    float x = r_hat[pidx*3+0];
    float y = r_hat[pidx*3+1];
    float z = r_hat[pidx*3+2];
    const float SQ3=1.7320508075688772f;
    const float C15=3.8729833462074170f;
    const float C5H=1.1180339887498949f;
    float y1a=SQ3*x, y1b=SQ3*y, y1c=SQ3*z;
    s_YT[0*264+j]=f2bf(mk);
    s_YT[1*264+j]=f2bf(y1a*mk);
    s_YT[2*264+j]=f2bf(y1b*mk);
    s_YT[3*264+j]=f2bf(y1c*mk);
    s_YT[4*264+j]=f2bf(C15*x*y*mk);
    s_YT[5*264+j]=f2bf(C15*y*z*mk);
    s_YT[6*264+j]=f2bf(C5H*(3.f*z*z-1.f)*mk);
    s_YT[7*264+j]=f2bf(C15*x*z*mk);
    s_YT[8*264+j]=f2bf(0.5f*C15*(x*x-y*y)*mk);
    s_YT[9*264+j]=f2bf(mk);
    s_YT[10*264+j]=0;                     // zero row for masked-off lanes
    s_Y1r[0*264+j]=f2bf(y1a);
    s_Y1r[1*264+j]=f2bf(y1b);
    s_Y1r[2*264+j]=f2bf(y1c);
  }

  const float* rbf_blk = rbf + (size_t)bi*Nn*Rr;
  const float* htb     = h_ws + (size_t)b*Dd*Nn;   // h_T[b][d][i]

  // ---- stage rbf as bf16 (row stride 40): packed pairs ----
  for (int idx=tid; idx<Nn*Rr/2; idx+=512){
    int j = idx >> 4, r2 = (idx & 15)*2;
    const float* src = &rbf_blk[j*Rr + r2];
    float v0 = src[0], v1 = src[1];
    *(u32*)&s_rbf[j*40 + r2] = cvtpk(v0, v1);
  }

  // ---- node_v B-fragment for the dot MFMA (wave's 16 d-cols) ----
  bf16x8 vBf;
  {
    const float* nv = node_v + (size_t)bi*3*Dd;
    int dd = dwb+cc;
    bf16x8 t = {0,0,0,0,0,0,0,0};
    if (q==0){
      t[0]=f2bfs(nv[0*Dd+dd]);
      t[1]=f2bfs(nv[1*Dd+dd]);
      t[2]=f2bfs(nv[2*Dd+dd]);
    }
    vBf=t;
  }

  // ---- per-lane LDS u16-index bases (accesses = base + small runtime chunk
  //      base + compile-time immediate) ----
  const int rbf_base = cc*40 + q*8;                 // + ch*2560 + jt*640
  const int hw_base  = cc*130 + w*16 + q*4;         // + buf*8320 + jt*2080
  const int af_base  = (hi5*8+lo2)*130 + q*8;       // + buf*8320 + g*4160 + mm*520 + ks*32

  __syncthreads();                       // setup + staging visible

  const f32x4 zf = {0.f,0.f,0.f,0.f};
  f32x4 accred = zf;

  // pipeline registers
  bf16x8 w1f;  f32x4 b1v4;               // GEMM1 weights of the pending chunk's p
  bf16x8 w2f[4]; float b2v;
  const u16* ytq;                        // per-p Y row base (+q*8 folded)

  // rb = u16-index base of the chunk in s_rbf (= ch*2560); bufn in {0,1}
  auto do_gemm1 = [&](int rb, int bufn){
    #pragma unroll
    for (int jt=0;jt<4;jt++){
      bf16x8 rbff = *(const bf16x8*)&s_rbf[rbf_base + rb + jt*640];
      f32x4 hc = __builtin_amdgcn_mfma_f32_16x16x32_bf16(w1f, rbff, zf, 0,0,0);
      float s0,s1,s2,s3;
      {
        float x0=hc[0]+b1v4[0], x1=hc[1]+b1v4[1], x2=hc[2]+b1v4[2], x3=hc[3]+b1v4[3];
        s0 = x0*__builtin_amdgcn_rcpf(1.f+__expf(-x0));
        s1 = x1*__builtin_amdgcn_rcpf(1.f+__expf(-x1));
        s2 = x2*__builtin_amdgcn_rcpf(1.f+__expf(-x2));
        s3 = x3*__builtin_amdgcn_rcpf(1.f+__expf(-x3));
      }
      u32x2 pk = { cvtpk(s0, s1), cvtpk(s2, s3) };
      *(u32x2*)&s_hid[bufn*8320 + hw_base + jt*2080] = pk;
    }
  };

  // choff = ch*64 (j units); bufx in {0,1}
  auto do_gemm2 = [&](int choff, int bufx, int p){
    f32x4 hql[2][2];
    if (p<3){
      #pragma unroll
      for (int g=0;g<2;g++)
        #pragma unroll
        for (int mm=0;mm<2;mm++)
          hql[g][mm] = *(const f32x4*)&htb[(size_t)(dwb+cc)*Nn + choff + g*32 + q*8 + mm*4];
    }
    #pragma unroll
    for (int g=0; g<2; g++){
      u32 bB[4];
      #pragma unroll
      for (int mm=0;mm<2;mm++){
        bf16x8 af[4];
        #pragma unroll
        for (int ks=0;ks<4;ks++)
          af[ks] = *(const bf16x8*)&s_hid[bufx*8320 + af_base + g*4160 + mm*520 + ks*32];

        f32x4 dotC;
        if (p==3){                       // dot(v, Y1): A rows follow the tile perm
          bf16x8 aY = {0,0,0,0,0,0,0,0};
          if (q==0){
            int jg = choff + g*32 + hi5*8 + mm*4 + lo2;
            aY[0]=(short)s_Y1r[0*264+jg];
            aY[1]=(short)s_Y1r[1*264+jg];
            aY[2]=(short)s_Y1r[2*264+jg];
          }
          dotC = __builtin_amdgcn_mfma_f32_16x16x32_bf16(aY, vBf, zf, 0,0,0);
        }

        f32x4 c2 = zf;
        #pragma unroll
        for (int ks=0;ks<4;ks++)
          c2 = __builtin_amdgcn_mfma_f32_16x16x32_bf16(af[ks], w2f[ks], c2, 0,0,0);
        float g0,g1,g2,g3;
        if (p<3){
          g0=(c2[0]+b2v)*hql[0][0][0], g1=(c2[1]+b2v)*hql[0][0][1];
          // (indexing via g/mm below; use the right hql slot)
          g0=(c2[0]+b2v)*hql[g][mm][0]; g1=(c2[1]+b2v)*hql[g][mm][1];
          g2=(c2[2]+b2v)*hql[g][mm][2]; g3=(c2[3]+b2v)*hql[g][mm][3];
        } else {
          g0=(c2[0]+b2v)*dotC[0]; g1=(c2[1]+b2v)*dotC[1];
          g2=(c2[2]+b2v)*dotC[2]; g3=(c2[3]+b2v)*dotC[3];
        }
        bB[mm*2+0] = cvtpk(g0, g1);
        bB[mm*2+1] = cvtpk(g2, g3);
      }
      // j-reduction MFMA over this 32-j group (B-frag from registers)
      bf16x8 aR = *(const bf16x8*)(ytq + choff + g*32);
      u32x4 bw = { bB[0], bB[1], bB[2], bB[3] };
      bf16x8 bG = __builtin_bit_cast(bf16x8, bw);
      accred = __builtin_amdgcn_mfma_f32_16x16x32_bf16(aR, bG, accred, 0,0,0);
    }
  };

  // prologue: p0 GEMM1 weights + chunk 0 -> buf0
  w1f  = *(const bf16x8*)&g_w1t[(dwb+cc)*Rr + q*8];
  b1v4 = *(const f32x4*)&r0b1[dwb + q*4];
  do_gemm1(0, 0);

  #pragma unroll 1
  for (int p=0;p<4;p++){
    // per-p GEMM2-side state (global reads: before barrier, latency overlaps)
    {
      const u16* W2T = g_w2t + p*Dd*Dd;
      #pragma unroll
      for (int ks=0;ks<4;ks++)
        w2f[ks] = *(const bf16x8*)&W2T[(dwb+cc)*Dd + ks*32 + q*8];
      const float* B2p = (p==0)?r0b2:(p==1)?r1b2:(p==2)?r2b2:r3b2;
      b2v = B2p[dwb + cc];
      const int lo = (p==0)?0:(p==1)?1:(p==2)?4:9;
      const int hi = (p==0)?0:(p==1)?3:(p==2)?8:9;
      ytq = &s_YT[((cc>=lo && cc<=hi)?cc:10)*264] + q*8;
    }
    // pair loop: u=0 handles chunks {0,1} (+prefetch g1 of ch2),
    //            u=1 handles chunks {2,3} (+prefetch g1 of next-p ch0)
    #pragma unroll 1
    for (int u=0; u<2; u++){
      const int rb0   = u*5120;          // s_rbf base of chunk 2u
      const int choff = u*128;           // j-offset of chunk 2u
      __syncthreads();
      do_gemm1(rb0 + 2560, 1);           // ch 2u+1 -> buf1
      do_gemm2(choff, 0, p);             // ch 2u   <- buf0
      __syncthreads();
      if (u==0){
        do_gemm1(rb0 + 5120, 0);         // ch 2 -> buf0
      } else if (p<3){
        w1f  = *(const bf16x8*)&g_w1t[(p+1)*Dd*Rr + (dwb+cc)*Rr + q*8];
        const float* B1n = (p==0)?r1b1:(p==1)?r2b1:r3b1;
        b1v4 = *(const f32x4*)&B1n[dwb + q*4];
        do_gemm1(0, 0);                  // next-p ch0 -> buf0
      }
      do_gemm2(choff + 64, 1, p);        // ch 2u+1 <- buf1
    }
  }

  // ---- scatter accred rows -> outputs / LN inputs (complete per wave) ----
  {
    const int d = dwb + cc;
    #pragma unroll
    for (int r=0;r<4;r++){
      const int rw = q*4 + r;
      float val = accred[r];
      if (rw==0)      s_msg[d] = val;
      else if (rw<=3) out_v[(size_t)bi*3*Dd + (size_t)(rw-1)*Dd + d] = val*v_scale[d];
      else if (rw<=8) out_t[(size_t)bi*5*Dd + (size_t)(rw-4)*Dd + d] = val*t_scale[d];
      else if (rw==9) s_xn[d] = val;
    }
  }
  __syncthreads();

  // ---- LayerNorm stats (wave 0) ----
  if (tid < 64){
    float a0=s_msg[tid]+s_xn[tid], a1=s_msg[tid+64]+s_xn[tid+64];
    float s1=a0+a1, s2=a0*a0+a1*a1;
    #pragma unroll
    for (int off=1;off<64;off<<=1){
      s1 += __shfl_xor(s1,off);
      s2 += __shfl_xor(s2,off);
    }
    if (tid==0){
      float m   = s1*(1.f/Dd);
      float var = fmaxf(s2*(1.f/Dd) - m*m, 0.f);
      s_mv[0]=m;
      s_mv[1]=rsqrtf(var+1e-5f);
    }
  }
  __syncthreads();
  if (tid < Dd){
    float msg = s_msg[tid]+s_xn[tid];
    s_xn[tid] = (msg - s_mv[0])*s_mv[1]*ln_g[tid] + ln_b[tid];
  }
  __syncthreads();

  // ---- delta_s = xn @ out_w + out_b (4 k-segments across 512 threads) ----
  {
    int dp = tid & 127, seg = tid >> 7;
    float pa = 0.f;
    #pragma unroll 8
    for (int k=seg*32;k<seg*32+32;k++)
      pa += s_xn[k]*out_w[k*Dd+dp];
    s_part[seg*Dd+dp]=pa;
  }
  __syncthreads();
  if (tid < Dd)
    out_s[(size_t)bi*Dd+tid] = s_part[tid]+s_part[Dd+tid]+s_part[2*Dd+tid]+s_part[3*Dd+tid]+out_b[tid];
}

extern "C" void kernel_launch(void* const* d_in, const int* in_sizes, int n_in,
                              void* d_out, int out_size, void* d_ws, size_t ws_size,
                              hipStream_t stream) {
  const float* node_s = (const float*)d_in[0];
  const float* node_v = (const float*)d_in[1];
  // d_in[2] = node_t (unused by reference)
  const float* rbf    = (const float*)d_in[3];
  const float* r_hat  = (const float*)d_in[4];
  const float* maskp  = (const float*)d_in[5];
  const float* r0w1=(const float*)d_in[6],  *r0b1=(const float*)d_in[7];
  const float* r0w2=(const float*)d_in[8],  *r0b2=(const float*)d_in[9];
  const float* r1w1=(const float*)d_in[10], *r1b1=(const float*)d_in[11];
  const float* r1w2=(const float*)d_in[12], *r1b2=(const float*)d_in[13];
  const float* r2w1=(const float*)d_in[14], *r2b1=(const float*)d_in[15];
  const float* r2w2=(const float*)d_in[16], *r2b2=(const float*)d_in[17];
  const float* r3w1=(const float*)d_in[18], *r3b1=(const float*)d_in[19];
  const float* r3w2=(const float*)d_in[20], *r3b2=(const float*)d_in[21];
  const float* src_w  =(const float*)d_in[22];
  const float* ln_g   =(const float*)d_in[23];
  const float* ln_b   =(const float*)d_in[24];
  const float* out_w  =(const float*)d_in[25];
  const float* out_b  =(const float*)d_in[26];
  const float* v_scale=(const float*)d_in[27];
  const float* t_scale=(const float*)d_in[28];

  float* h_ws = (float*)d_ws;                    // h_T: 2*128*256 f32 = 256 KiB
  float* out_s = (float*)d_out;
  float* out_v = out_s + (size_t)Bb*Nn*Dd;
  float* out_t = out_v + (size_t)Bb*Nn*3*Dd;

  prep_kernel<<<dim3(Bb*Nn + 32), dim3(128), 0, stream>>>(
      node_s, src_w,
      r0w1, r1w1, r2w1, r3w1, r0w2, r1w2, r2w2, r3w2,
      h_ws);
  se3_mfma17<<<dim3(Bb*Nn), dim3(512), 0, stream>>>(
      node_v, rbf, r_hat, maskp,
      r0b1,r0b2, r1b1,r1b2, r2b1,r2b2, r3b1,r3b2,
      ln_g, ln_b, out_w, out_b, v_scale, t_scale,
      h_ws, out_s, out_v, out_t);
}